// Round 12
// baseline (987.988 us; speedup 1.0000x reference)
//
#include <hip/hip_runtime.h>
#include <hip/hip_fp16.h>
#include <math.h>

#define N 8192
#define D 128

typedef _Float16 f16x4 __attribute__((ext_vector_type(4)));
typedef _Float16 f16x8 __attribute__((ext_vector_type(8)));
typedef float    f32x4 __attribute__((ext_vector_type(4)));

// ---------------------------------------------------------------------------
// FUSED: bit-packed mask build (blocks 0..N-1, ballot - no atomics) +
// layer-0 Q/K/V projection (blocks N..N+N/8-1). R12: the gather is gone -
// 11 rounds showed no gather-based attention escapes the divergent-request
// stall (~150us/call at 20% VALU, 2% HBM, 0% MFMA). Dense MFMA flash needs
// only mask BITS: bits[i][j>>5]. 8 MB, built from the 268 MB mask read.
// ---------------------------------------------------------------------------
__global__ __launch_bounds__(256) void bits_qkv(const int* __restrict__ mask,
                                                unsigned* __restrict__ bits,
                                                const float* __restrict__ A,
                                                const float* __restrict__ Wq, const float* __restrict__ bq,
                                                const float* __restrict__ Wk, const float* __restrict__ bk,
                                                const float* __restrict__ Wv, const float* __restrict__ bv,
                                                __half* __restrict__ Qo, __half* __restrict__ Ko,
                                                __half* __restrict__ Vo,
                                                float* __restrict__ copy_out) {
    __shared__ float As[8][D];
    const int tid = threadIdx.x;

    if (blockIdx.x < N) {
        const int i    = blockIdx.x;
        const int wave = tid >> 6;
        const int lane = tid & 63;
        const unsigned* row = (const unsigned*)(mask + (size_t)i * N);
        #pragma unroll 4
        for (int c = 0; c < 32; ++c) {
            const int base = c * 256 + wave * 64;       // 256 words per c across 4 waves
            const unsigned w = row[base + lane];        // coalesced 256B per wave
            const unsigned long long b = __ballot(w != 0);
            if (lane == 0)
                *(unsigned long long*)(bits + (size_t)i * 256 + (base >> 5)) = b;
        }
        return;
    }

    // ---- layer-0 QKV projection + fused output-0 copy ----
    const int r   = tid >> 5;
    const int jg  = tid & 31;
    const int i0  = (blockIdx.x - N) * 8;

    const float4 av = ((const float4*)(A + (size_t)i0 * D))[tid];
    ((float4*)&As[0][0])[tid] = av;
    ((float4*)(copy_out + (size_t)i0 * D))[tid] = av;
    __syncthreads();

    const float* Ws[3] = {Wq, Wk, Wv};
    const float* bs[3] = {bq, bk, bv};
    __half* Os[3] = {Qo, Ko, Vo};

    #pragma unroll
    for (int m = 0; m < 3; ++m) {
        float4 acc = *(const float4*)(bs[m] + 4 * jg);
        const float* W = Ws[m];
        #pragma unroll 8
        for (int k4 = 0; k4 < 32; ++k4) {
            const float4 a4 = *(const float4*)&As[r][4 * k4];
            const float* wb = W + (size_t)(4 * k4) * D + 4 * jg;
            const float4 w0 = *(const float4*)(wb);
            const float4 w1 = *(const float4*)(wb + D);
            const float4 w2 = *(const float4*)(wb + 2 * D);
            const float4 w3 = *(const float4*)(wb + 3 * D);
            acc.x += a4.x * w0.x + a4.y * w1.x + a4.z * w2.x + a4.w * w3.x;
            acc.y += a4.x * w0.y + a4.y * w1.y + a4.z * w2.y + a4.w * w3.y;
            acc.z += a4.x * w0.z + a4.y * w1.z + a4.z * w2.z + a4.w * w3.z;
            acc.w += a4.x * w0.w + a4.y * w1.w + a4.z * w2.w + a4.w * w3.w;
        }
        f16x4 h;
        h[0] = (_Float16)acc.x; h[1] = (_Float16)acc.y;
        h[2] = (_Float16)acc.z; h[3] = (_Float16)acc.w;
        *(f16x4*)(Os[m] + (size_t)(i0 + r) * D + 4 * jg) = h;
    }
}

// ---------------------------------------------------------------------------
// R12 DENSE MFMA FLASH ATTENTION. Grid 256 = 128 query-tiles(64) x 2 key
// halves (split-K, unnormalized partials; combine folded into next GEMM).
// Block: 256 thr = 4 waves x 16 queries. Per 64-key tile:
//   stage K[64][128] + V^T[128][64] (XOR-swizzled: row-stride 256B/128B is
//   a 16-way bank conflict for the b128 fragment reads; ^((row&7)<<4) fixes
//   it - guide G4) + 64x2 mask words -> barrier ->
//   QK^T: 4 key-subtiles x 4 d-chunks of mfma_f32_16x16x32_f16
//   (A=Q regs, B=K rows; S C-layout: col=lane&15=key, row=(lane>>4)*4+r=q
//   [m89-verified]) -> p = maskbit ? exp(s/sqrt(128)) : 0 (scores ~N(0,1):
//   no max-subtraction needed) -> P to swizzled LDS (f16) ->
//   PV: 2 key-chunks x 8 d-subtiles (A=P rows, B=V^T rows) -> barrier.
// k-index mapping safety: A and B fragments use the SAME assumed k formula
// ((lane>>4)*8+e); any shared k-permutation cancels in the reduction.
// No neighbor lists, no gather: KV streams SEQUENTIALLY (256 blocks x 2MB
// = 512MB/layer from L2/L3 ~15-20us), MFMA does the 34 GFLOP/layer (~5us
// issue). Expected ~30-50us/layer vs 150 for every gather variant (R0-R11).
// ---------------------------------------------------------------------------
__global__ __launch_bounds__(256) void flash_attn(const __half* __restrict__ Q,
                                                  const __half* __restrict__ K,
                                                  const __half* __restrict__ V,
                                                  const unsigned* __restrict__ bits,
                                                  float* __restrict__ accP,
                                                  float* __restrict__ denP) {
    const int qt   = blockIdx.x >> 1;    // query tile (64 rows)
    const int h    = blockIdx.x & 1;     // key half
    const int tid  = threadIdx.x;
    const int wave = tid >> 6;
    const int lane = tid & 63;
    const int l15  = lane & 15;
    const int lg   = lane >> 4;          // 0..3

    __shared__ char lds[41472];
    // [0,16384)      K_lds [64 keys][128 d] f16, swz ^((key&7)<<4)
    // [16384,32768)  V_t  [128 d][64 keys] f16, swz ^((d&7)<<4)
    // [32768,40960)  P    [4 waves][16 q][64 keys] f16, swz ^((q&7)<<4)
    // [40960,41472)  mask u32 [64 q][2 words]
    unsigned* mask_lds = (unsigned*)(lds + 40960);

    const int qbase = qt * 64 + wave * 16;

    // hoist Q fragments: A[q=l15][d-chunk c]: 8 f16 at (lane>>4)*8 within chunk
    f16x8 qf[4];
    #pragma unroll
    for (int c = 0; c < 4; ++c)
        qf[c] = *(const f16x8*)(Q + (size_t)(qbase + l15) * D + c * 32 + lg * 8);

    f32x4 Oacc[8];
    #pragma unroll
    for (int ds = 0; ds < 8; ++ds) Oacc[ds] = (f32x4){0.f, 0.f, 0.f, 0.f};
    float den[4] = {0.f, 0.f, 0.f, 0.f};

    const float scale = 0.088388347648318447f;  // 1/sqrt(128)

    for (int t = 0; t < 64; ++t) {
        const int kb = h * 4096 + t * 64;

        // ---- stage K (b128 swizzled) + V^T (scalar f16 swizzled) ----
        #pragma unroll
        for (int cc = 0; cc < 4; ++cc) {
            const int idx  = tid + cc * 256;          // 0..1023
            const int krow = idx >> 4;
            const int dp   = (idx & 15) * 8;
            const f16x8 k8 = *(const f16x8*)(K + (size_t)(kb + krow) * D + dp);
            *(f16x8*)(lds + ((krow * 256 + dp * 2) ^ ((krow & 7) << 4))) = k8;
            const f16x8 v8 = *(const f16x8*)(V + (size_t)(kb + krow) * D + dp);
            #pragma unroll
            for (int e = 0; e < 8; ++e) {
                const int d = dp + e;
                *(_Float16*)(lds + 16384 + ((d * 128 + krow * 2) ^ ((d & 7) << 4))) = v8[e];
            }
        }
        if (tid < 128)   // mask: 64 q x 2 words for this key tile
            mask_lds[tid] = bits[(size_t)(qt * 64 + (tid >> 1)) * 256 + (kb >> 5) + (tid & 1)];
        __syncthreads();

        // ---- QK^T + mask + exp + P-write (per wave) ----
        #pragma unroll
        for (int kt = 0; kt < 4; ++kt) {
            f32x4 s = (f32x4){0.f, 0.f, 0.f, 0.f};
            const int key = kt * 16 + l15;
            #pragma unroll
            for (int c = 0; c < 4; ++c) {
                const f16x8 b = *(const f16x8*)(lds +
                    ((key * 256 + (c * 32 + lg * 8) * 2) ^ ((key & 7) << 4)));
                s = __builtin_amdgcn_mfma_f32_16x16x32_f16(qf[c], b, s, 0, 0, 0);
            }
            #pragma unroll
            for (int r = 0; r < 4; ++r) {
                const int q  = lg * 4 + r;                       // q within wave tile
                const unsigned mw = mask_lds[(wave * 16 + q) * 2 + (key >> 5)];
                const float p = ((mw >> (key & 31)) & 1u) ? __expf(s[r] * scale) : 0.f;
                den[r] += p;
                *(_Float16*)(lds + 32768 + wave * 2048 +
                             ((q * 128 + key * 2) ^ ((q & 7) << 4))) = (_Float16)p;
            }
        }

        // ---- PV: O += P @ V ----
        #pragma unroll
        for (int kc = 0; kc < 2; ++kc) {
            const f16x8 a = *(const f16x8*)(lds + 32768 + wave * 2048 +
                ((l15 * 128 + (kc * 32 + lg * 8) * 2) ^ ((l15 & 7) << 4)));
            #pragma unroll
            for (int ds = 0; ds < 8; ++ds) {
                const int d = ds * 16 + l15;
                const f16x8 b = *(const f16x8*)(lds + 16384 +
                    ((d * 128 + (kc * 32 + lg * 8) * 2) ^ ((d & 7) << 4)));
                Oacc[ds] = __builtin_amdgcn_mfma_f32_16x16x32_f16(a, b, Oacc[ds], 0, 0, 0);
            }
        }
        __syncthreads();
    }

    // denominator: reduce across the 16 key-lanes of each row-group
    #pragma unroll
    for (int r = 0; r < 4; ++r) {
        den[r] += __shfl_xor(den[r], 1);
        den[r] += __shfl_xor(den[r], 2);
        den[r] += __shfl_xor(den[r], 4);
        den[r] += __shfl_xor(den[r], 8);
    }

    // store UNNORMALIZED partials (combine happens in the next GEMM's stage)
    float* ap = accP + (size_t)h * N * D;
    #pragma unroll
    for (int ds = 0; ds < 8; ++ds)
        #pragma unroll
        for (int r = 0; r < 4; ++r)
            ap[(size_t)(qbase + lg * 4 + r) * D + ds * 16 + l15] = Oacc[ds][r];
    if (l15 == 0) {
        #pragma unroll
        for (int r = 0; r < 4; ++r)
            denP[h * N + qbase + lg * 4 + r] = den[r];
    }
}

// ---------------------------------------------------------------------------
// Combine split-K partials -> h = (acc0+acc1)/(den0+den1), then
// h@Wo+bo -> Hout, then next layer's Q/K/V (f16).
// ---------------------------------------------------------------------------
__global__ __launch_bounds__(256) void gemmO_qkv(const float* __restrict__ accP,
                                                 const float* __restrict__ denP,
                                                 const float* __restrict__ Wo, const float* __restrict__ bo,
                                                 float* __restrict__ Hout,
                                                 const float* __restrict__ Wq, const float* __restrict__ bq,
                                                 const float* __restrict__ Wk, const float* __restrict__ bk,
                                                 const float* __restrict__ Wv, const float* __restrict__ bv,
                                                 __half* __restrict__ Qo, __half* __restrict__ Ko,
                                                 __half* __restrict__ Vo) {
    __shared__ float As[8][D];
    __shared__ float Hs[8][D];
    const int tid = threadIdx.x;
    const int r   = tid >> 5;
    const int jg  = tid & 31;
    const int i0  = blockIdx.x * 8;

    {
        const int i = i0 + (tid >> 5);
        const float inv = 1.0f / (denP[i] + denP[N + i]);
        const float4 a0 = ((const float4*)(accP + (size_t)i0 * D))[tid];
        const float4 a1 = ((const float4*)(accP + (size_t)(N + i0) * D))[tid];
        float4 v;
        v.x = (a0.x + a1.x) * inv; v.y = (a0.y + a1.y) * inv;
        v.z = (a0.z + a1.z) * inv; v.w = (a0.w + a1.w) * inv;
        ((float4*)&As[0][0])[tid] = v;
    }
    __syncthreads();

    {
        float4 acc = *(const float4*)(bo + 4 * jg);
        #pragma unroll 8
        for (int k4 = 0; k4 < 32; ++k4) {
            const float4 a4 = *(const float4*)&As[r][4 * k4];
            const float* wb = Wo + (size_t)(4 * k4) * D + 4 * jg;
            const float4 w0 = *(const float4*)(wb);
            const float4 w1 = *(const float4*)(wb + D);
            const float4 w2 = *(const float4*)(wb + 2 * D);
            const float4 w3 = *(const float4*)(wb + 3 * D);
            acc.x += a4.x * w0.x + a4.y * w1.x + a4.z * w2.x + a4.w * w3.x;
            acc.y += a4.x * w0.y + a4.y * w1.y + a4.z * w2.y + a4.w * w3.y;
            acc.z += a4.x * w0.z + a4.y * w1.z + a4.z * w2.z + a4.w * w3.z;
            acc.w += a4.x * w0.w + a4.y * w1.w + a4.z * w2.w + a4.w * w3.w;
        }
        *(float4*)(Hout + (size_t)(i0 + r) * D + 4 * jg) = acc;
        *(float4*)&Hs[r][4 * jg] = acc;
    }
    __syncthreads();

    const float* Ws[3] = {Wq, Wk, Wv};
    const float* bs[3] = {bq, bk, bv};
    __half* Os[3] = {Qo, Ko, Vo};
    #pragma unroll
    for (int m = 0; m < 3; ++m) {
        float4 acc = *(const float4*)(bs[m] + 4 * jg);
        const float* W = Ws[m];
        #pragma unroll 8
        for (int k4 = 0; k4 < 32; ++k4) {
            const float4 a4 = *(const float4*)&Hs[r][4 * k4];
            const float* wb = W + (size_t)(4 * k4) * D + 4 * jg;
            const float4 w0 = *(const float4*)(wb);
            const float4 w1 = *(const float4*)(wb + D);
            const float4 w2 = *(const float4*)(wb + 2 * D);
            const float4 w3 = *(const float4*)(wb + 3 * D);
            acc.x += a4.x * w0.x + a4.y * w1.x + a4.z * w2.x + a4.w * w3.x;
            acc.y += a4.x * w0.y + a4.y * w1.y + a4.z * w2.y + a4.w * w3.y;
            acc.z += a4.x * w0.z + a4.y * w1.z + a4.z * w2.z + a4.w * w3.z;
            acc.w += a4.x * w0.w + a4.y * w1.w + a4.z * w2.w + a4.w * w3.w;
        }
        f16x4 hh;
        hh[0] = (_Float16)acc.x; hh[1] = (_Float16)acc.y;
        hh[2] = (_Float16)acc.z; hh[3] = (_Float16)acc.w;
        *(f16x4*)(Os[m] + (size_t)(i0 + r) * D + 4 * jg) = hh;
    }
}

// ---------------------------------------------------------------------------
// Final: combine partials -> h, then h@Wo+bo -> C (fp32).
// ---------------------------------------------------------------------------
__global__ __launch_bounds__(256) void gemm_bias(const float* __restrict__ accP,
                                                 const float* __restrict__ denP,
                                                 const float* __restrict__ W,
                                                 const float* __restrict__ bias,
                                                 float* __restrict__ C) {
    __shared__ float As[8][D];
    const int tid = threadIdx.x;
    const int r   = tid >> 5;
    const int jg  = tid & 31;
    const int i0  = blockIdx.x * 8;

    {
        const int i = i0 + (tid >> 5);
        const float inv = 1.0f / (denP[i] + denP[N + i]);
        const float4 a0 = ((const float4*)(accP + (size_t)i0 * D))[tid];
        const float4 a1 = ((const float4*)(accP + (size_t)(N + i0) * D))[tid];
        float4 v;
        v.x = (a0.x + a1.x) * inv; v.y = (a0.y + a1.y) * inv;
        v.z = (a0.z + a1.z) * inv; v.w = (a0.w + a1.w) * inv;
        ((float4*)&As[0][0])[tid] = v;
    }
    __syncthreads();

    float4 acc = *(const float4*)(bias + 4 * jg);
    #pragma unroll 8
    for (int k4 = 0; k4 < 32; ++k4) {
        const float4 a4 = *(const float4*)&As[r][4 * k4];
        const float* wb = W + (size_t)(4 * k4) * D + 4 * jg;
        const float4 w0 = *(const float4*)(wb);
        const float4 w1 = *(const float4*)(wb + D);
        const float4 w2 = *(const float4*)(wb + 2 * D);
        const float4 w3 = *(const float4*)(wb + 3 * D);
        acc.x += a4.x * w0.x + a4.y * w1.x + a4.z * w2.x + a4.w * w3.x;
        acc.y += a4.x * w0.y + a4.y * w1.y + a4.z * w2.y + a4.w * w3.y;
        acc.z += a4.x * w0.z + a4.y * w1.z + a4.z * w2.z + a4.w * w3.z;
        acc.w += a4.x * w0.w + a4.y * w1.w + a4.z * w2.w + a4.w * w3.w;
    }
    *(float4*)(C + (size_t)(i0 + r) * D + 4 * jg) = acc;
}

extern "C" void kernel_launch(void* const* d_in, const int* in_sizes, int n_in,
                              void* d_out, int out_size, void* d_ws, size_t ws_size,
                              hipStream_t stream) {
    const float* features = (const float*)d_in[0];
    const int*   mask     = (const int*)d_in[1];
    const float* Wq = (const float*)d_in[2];
    const float* bq = (const float*)d_in[3];
    const float* Wk = (const float*)d_in[4];
    const float* bk = (const float*)d_in[5];
    const float* Wv = (const float*)d_in[6];
    const float* bv = (const float*)d_in[7];
    const float* Wo = (const float*)d_in[8];
    const float* bo = (const float*)d_in[9];
    float* out = (float*)d_out;

    // workspace (~22 MB): bits | Qf | Kf | Vf | accP | denP
    char* base = (char*)d_ws;
    unsigned* bits = (unsigned*)base;                                   // 8 MB
    __half* Qf = (__half*)(base + (size_t)N * 256 * 4);                 // 2 MB
    __half* Kf = Qf + (size_t)N * D;                                    // 2 MB
    __half* Vf = Kf + (size_t)N * D;                                    // 2 MB
    float* accP = (float*)(Vf + (size_t)N * D);                         // 8 MB (2 halves)
    float* denP = accP + (size_t)2 * N * D;                             // 64 KB

    // dispatch 1: mask bits (ballot) + layer-0 QKV (+ out[0] copy)
    bits_qkv<<<N + N / 8, 256, 0, stream>>>(mask, bits,
                                            features, Wq, bq, Wk, bk, Wv, bv,
                                            Qf, Kf, Vf, out);
    // layer 0: dense MFMA flash (split-K x2, unnormalized partials)
    flash_attn<<<256, 256, 0, stream>>>(Qf, Kf, Vf, bits, accP, denP);
    gemmO_qkv<<<N / 8, 256, 0, stream>>>(accP, denP, Wo, bo, out + (size_t)N * D,
                                         Wq + D * D, bq + D, Wk + D * D, bk + D,
                                         Wv + D * D, bv + D, Qf, Kf, Vf);
    // layer 1
    flash_attn<<<256, 256, 0, stream>>>(Qf, Kf, Vf, bits, accP, denP);
    gemm_bias<<<N / 8, 256, 0, stream>>>(accP, denP, Wo + D * D, bo + D,
                                         out + (size_t)2 * N * D);
}

// Round 13
// 729.889 us; speedup vs baseline: 1.3536x; 1.3536x over previous
//
#include <hip/hip_runtime.h>
#include <hip/hip_fp16.h>
#include <math.h>

#define N 8192
#define D 128

typedef _Float16 f16x4 __attribute__((ext_vector_type(4)));
typedef _Float16 f16x8 __attribute__((ext_vector_type(8)));
typedef float    f32x4 __attribute__((ext_vector_type(4)));

// ---------------------------------------------------------------------------
// FUSED: bit-packed mask build (blocks 0..N-1) + layer-0 Q/K/V projection
// (blocks N..N+N/8-1).
// R13 bits path: int4 loads (16B/lane, the proven build_adj pattern; R12's
// scalar 4B loads ran at 698 GB/s = 4x slow) -> nibble per int4 in LDS ->
// 256 threads assemble one u32 word each (8 nibbles). No ballot, no atomics.
// V is written TRANSPOSED to global Vt[d][key] so flash_attn can stage V^T
// tiles with coalesced b128 ops (R12's in-kernel scalar transpose staging
// was ~32 conflicted ds_write_u16/thread/tile - the main regression).
// ---------------------------------------------------------------------------
__global__ __launch_bounds__(256) void bits_qkv(const int* __restrict__ mask,
                                                unsigned* __restrict__ bits,
                                                const float* __restrict__ A,
                                                const float* __restrict__ Wq, const float* __restrict__ bq,
                                                const float* __restrict__ Wk, const float* __restrict__ bk,
                                                const float* __restrict__ Wv, const float* __restrict__ bv,
                                                __half* __restrict__ Qo, __half* __restrict__ Ko,
                                                __half* __restrict__ Vt,
                                                float* __restrict__ copy_out) {
    __shared__ float As[8][D];
    const int tid = threadIdx.x;

    if (blockIdx.x < N) {
        const int i = blockIdx.x;
        __shared__ unsigned char nib[2048];          // 1 nibble-byte per 4 columns
        const int4* row = (const int4*)(mask + (size_t)i * N);
        #pragma unroll
        for (int c = 0; c < 8; ++c) {
            const int idx = tid + c * 256;           // 0..2047, coalesced int4
            const int4 m4 = row[idx];
            nib[idx] = (unsigned char)((m4.x ? 1 : 0) | (m4.y ? 2 : 0) |
                                       (m4.z ? 4 : 0) | (m4.w ? 8 : 0));
        }
        __syncthreads();
        // word tid covers columns [32*tid, 32*tid+32) = nibbles [8*tid, 8*tid+8)
        const unsigned long long n8 = *(const unsigned long long*)&nib[8 * tid];
        unsigned word = 0;
        #pragma unroll
        for (int b = 0; b < 8; ++b)
            word |= ((unsigned)((n8 >> (8 * b)) & 0xFull)) << (4 * b);
        bits[(size_t)i * 256 + tid] = word;
        return;
    }

    // ---- layer-0 QKV projection + fused output-0 copy ----
    const int r   = tid >> 5;
    const int jg  = tid & 31;
    const int i0  = (blockIdx.x - N) * 8;

    const float4 av = ((const float4*)(A + (size_t)i0 * D))[tid];
    ((float4*)&As[0][0])[tid] = av;
    ((float4*)(copy_out + (size_t)i0 * D))[tid] = av;
    __syncthreads();

    const float* Ws[3] = {Wq, Wk, Wv};
    const float* bs[3] = {bq, bk, bv};

    #pragma unroll
    for (int m = 0; m < 3; ++m) {
        float4 acc = *(const float4*)(bs[m] + 4 * jg);
        const float* W = Ws[m];
        #pragma unroll 8
        for (int k4 = 0; k4 < 32; ++k4) {
            const float4 a4 = *(const float4*)&As[r][4 * k4];
            const float* wb = W + (size_t)(4 * k4) * D + 4 * jg;
            const float4 w0 = *(const float4*)(wb);
            const float4 w1 = *(const float4*)(wb + D);
            const float4 w2 = *(const float4*)(wb + 2 * D);
            const float4 w3 = *(const float4*)(wb + 3 * D);
            acc.x += a4.x * w0.x + a4.y * w1.x + a4.z * w2.x + a4.w * w3.x;
            acc.y += a4.x * w0.y + a4.y * w1.y + a4.z * w2.y + a4.w * w3.y;
            acc.z += a4.x * w0.z + a4.y * w1.z + a4.z * w2.z + a4.w * w3.z;
            acc.w += a4.x * w0.w + a4.y * w1.w + a4.z * w2.w + a4.w * w3.w;
        }
        if (m == 2) {   // V transposed: Vt[d][row]
            const int i = i0 + r;
            Vt[(size_t)(4 * jg)     * N + i] = (__half)(_Float16)acc.x;
            Vt[(size_t)(4 * jg + 1) * N + i] = (__half)(_Float16)acc.y;
            Vt[(size_t)(4 * jg + 2) * N + i] = (__half)(_Float16)acc.z;
            Vt[(size_t)(4 * jg + 3) * N + i] = (__half)(_Float16)acc.w;
        } else {
            f16x4 h;
            h[0] = (_Float16)acc.x; h[1] = (_Float16)acc.y;
            h[2] = (_Float16)acc.z; h[3] = (_Float16)acc.w;
            __half* O = (m == 0) ? Qo : Ko;
            *(f16x4*)(O + (size_t)(i0 + r) * D + 4 * jg) = h;
        }
    }
}

// ---------------------------------------------------------------------------
// R13 DENSE MFMA FLASH ATTENTION. Grid 256 = 128 query-tiles(64) x 2 key
// halves (split-K, unnormalized partials; combine folded into next GEMM).
// Block: 256 thr = 4 waves x 16 queries. Per 64-key tile:
//   stage K[64][128] (b128, swz ^((key&7)<<4)) + V^T tile from global
//   Vt[d][key] (b128, swz ^((d&7)<<4)) + 64x2 mask words -> barrier ->
//   QK^T: 4 key-subtiles x 4 d-chunks mfma_f32_16x16x32_f16 (C-layout:
//   col=lane&15=key, row=(lane>>4)*4+r=q; m89-verified, R12 confirmed
//   end-to-end absmax 0.0078) -> p = maskbit ? exp(s/sqrt(128)) : 0 ->
//   P to swizzled LDS f16 (16 scalar writes/thread, 2-way conflict=free)
//   -> PV: 2 key-chunks x 8 d-subtiles -> barrier.
// All staging is b128 now: R12's scalar V-transpose (32 conflicted
// ds_write_u16/thread/tile) is gone - Vt comes pre-transposed from the
// QKV gemm. KV streams sequentially; no divergent gather anywhere.
// ---------------------------------------------------------------------------
__global__ __launch_bounds__(256) void flash_attn(const __half* __restrict__ Q,
                                                  const __half* __restrict__ K,
                                                  const __half* __restrict__ Vt,
                                                  const unsigned* __restrict__ bits,
                                                  float* __restrict__ accP,
                                                  float* __restrict__ denP) {
    const int qt   = blockIdx.x >> 1;    // query tile (64 rows)
    const int h    = blockIdx.x & 1;     // key half
    const int tid  = threadIdx.x;
    const int wave = tid >> 6;
    const int lane = tid & 63;
    const int l15  = lane & 15;
    const int lg   = lane >> 4;          // 0..3

    __shared__ char lds[41472];
    // [0,16384)      K_lds [64 keys][128 d] f16, swz ^((key&7)<<4)
    // [16384,32768)  V_t  [128 d][64 keys] f16, swz ^((d&7)<<4)
    // [32768,40960)  P    [4 waves][16 q][64 keys] f16, swz ^((q&7)<<4)
    // [40960,41472)  mask u32 [64 q][2 words]
    unsigned* mask_lds = (unsigned*)(lds + 40960);

    const int qbase = qt * 64 + wave * 16;

    // hoist Q fragments: A[q=l15][d-chunk c]: 8 f16 at lg*8 within chunk
    f16x8 qf[4];
    #pragma unroll
    for (int c = 0; c < 4; ++c)
        qf[c] = *(const f16x8*)(Q + (size_t)(qbase + l15) * D + c * 32 + lg * 8);

    f32x4 Oacc[8];
    #pragma unroll
    for (int ds = 0; ds < 8; ++ds) Oacc[ds] = (f32x4){0.f, 0.f, 0.f, 0.f};
    float den[4] = {0.f, 0.f, 0.f, 0.f};

    const float scale = 0.088388347648318447f;  // 1/sqrt(128)

    for (int t = 0; t < 64; ++t) {
        const int kb = h * 4096 + t * 64;

        // ---- stage K tile + V^T tile, all b128 ----
        #pragma unroll
        for (int cc = 0; cc < 4; ++cc) {
            const int idx  = tid + cc * 256;          // 0..1023
            // K: [key][d]: 16 lanes per key row, 256B contiguous per row
            const int krow = idx >> 4;
            const int dp   = (idx & 15) * 8;
            const f16x8 k8 = *(const f16x8*)(K + (size_t)(kb + krow) * D + dp);
            *(f16x8*)(lds + ((krow * 256 + dp * 2) ^ ((krow & 7) << 4))) = k8;
            // V^T: [d][key]: 8 lanes per d row, 128B contiguous per row
            const int d    = idx >> 3;
            const int kg   = (idx & 7) * 8;
            const f16x8 v8 = *(const f16x8*)(Vt + (size_t)d * N + kb + kg);
            *(f16x8*)(lds + 16384 + ((d * 128 + kg * 2) ^ ((d & 7) << 4))) = v8;
        }
        if (tid < 128)   // mask: 64 q x 2 words for this key tile
            mask_lds[tid] = bits[(size_t)(qt * 64 + (tid >> 1)) * 256 + (kb >> 5) + (tid & 1)];
        __syncthreads();

        // ---- QK^T + mask + exp + P-write (per wave) ----
        #pragma unroll
        for (int kt = 0; kt < 4; ++kt) {
            f32x4 s = (f32x4){0.f, 0.f, 0.f, 0.f};
            const int key = kt * 16 + l15;
            #pragma unroll
            for (int c = 0; c < 4; ++c) {
                const f16x8 b = *(const f16x8*)(lds +
                    ((key * 256 + (c * 32 + lg * 8) * 2) ^ ((key & 7) << 4)));
                s = __builtin_amdgcn_mfma_f32_16x16x32_f16(qf[c], b, s, 0, 0, 0);
            }
            #pragma unroll
            for (int r = 0; r < 4; ++r) {
                const int q  = lg * 4 + r;                       // q within wave tile
                const unsigned mw = mask_lds[(wave * 16 + q) * 2 + (key >> 5)];
                const float p = ((mw >> (key & 31)) & 1u) ? __expf(s[r] * scale) : 0.f;
                den[r] += p;
                *(_Float16*)(lds + 32768 + wave * 2048 +
                             ((q * 128 + key * 2) ^ ((q & 7) << 4))) = (_Float16)p;
            }
        }

        // ---- PV: O += P @ V ----
        #pragma unroll
        for (int kc = 0; kc < 2; ++kc) {
            const f16x8 a = *(const f16x8*)(lds + 32768 + wave * 2048 +
                ((l15 * 128 + (kc * 32 + lg * 8) * 2) ^ ((l15 & 7) << 4)));
            #pragma unroll
            for (int ds = 0; ds < 8; ++ds) {
                const int d = ds * 16 + l15;
                const f16x8 b = *(const f16x8*)(lds + 16384 +
                    ((d * 128 + (kc * 32 + lg * 8) * 2) ^ ((d & 7) << 4)));
                Oacc[ds] = __builtin_amdgcn_mfma_f32_16x16x32_f16(a, b, Oacc[ds], 0, 0, 0);
            }
        }
        __syncthreads();
    }

    // denominator: reduce across the 16 key-lanes of each row-group
    #pragma unroll
    for (int r = 0; r < 4; ++r) {
        den[r] += __shfl_xor(den[r], 1);
        den[r] += __shfl_xor(den[r], 2);
        den[r] += __shfl_xor(den[r], 4);
        den[r] += __shfl_xor(den[r], 8);
    }

    // store UNNORMALIZED partials (combine happens in the next GEMM's stage)
    float* ap = accP + (size_t)h * N * D;
    #pragma unroll
    for (int ds = 0; ds < 8; ++ds)
        #pragma unroll
        for (int r = 0; r < 4; ++r)
            ap[(size_t)(qbase + lg * 4 + r) * D + ds * 16 + l15] = Oacc[ds][r];
    if (l15 == 0) {
        #pragma unroll
        for (int r = 0; r < 4; ++r)
            denP[h * N + qbase + lg * 4 + r] = den[r];
    }
}

// ---------------------------------------------------------------------------
// Combine split-K partials -> h = (acc0+acc1)/(den0+den1), then
// h@Wo+bo -> Hout, then next layer's Q/K/Vt (f16).
// ---------------------------------------------------------------------------
__global__ __launch_bounds__(256) void gemmO_qkv(const float* __restrict__ accP,
                                                 const float* __restrict__ denP,
                                                 const float* __restrict__ Wo, const float* __restrict__ bo,
                                                 float* __restrict__ Hout,
                                                 const float* __restrict__ Wq, const float* __restrict__ bq,
                                                 const float* __restrict__ Wk, const float* __restrict__ bk,
                                                 const float* __restrict__ Wv, const float* __restrict__ bv,
                                                 __half* __restrict__ Qo, __half* __restrict__ Ko,
                                                 __half* __restrict__ Vt) {
    __shared__ float As[8][D];
    __shared__ float Hs[8][D];
    const int tid = threadIdx.x;
    const int r   = tid >> 5;
    const int jg  = tid & 31;
    const int i0  = blockIdx.x * 8;

    {
        const int i = i0 + (tid >> 5);
        const float inv = 1.0f / (denP[i] + denP[N + i]);
        const float4 a0 = ((const float4*)(accP + (size_t)i0 * D))[tid];
        const float4 a1 = ((const float4*)(accP + (size_t)(N + i0) * D))[tid];
        float4 v;
        v.x = (a0.x + a1.x) * inv; v.y = (a0.y + a1.y) * inv;
        v.z = (a0.z + a1.z) * inv; v.w = (a0.w + a1.w) * inv;
        ((float4*)&As[0][0])[tid] = v;
    }
    __syncthreads();

    {
        float4 acc = *(const float4*)(bo + 4 * jg);
        #pragma unroll 8
        for (int k4 = 0; k4 < 32; ++k4) {
            const float4 a4 = *(const float4*)&As[r][4 * k4];
            const float* wb = Wo + (size_t)(4 * k4) * D + 4 * jg;
            const float4 w0 = *(const float4*)(wb);
            const float4 w1 = *(const float4*)(wb + D);
            const float4 w2 = *(const float4*)(wb + 2 * D);
            const float4 w3 = *(const float4*)(wb + 3 * D);
            acc.x += a4.x * w0.x + a4.y * w1.x + a4.z * w2.x + a4.w * w3.x;
            acc.y += a4.x * w0.y + a4.y * w1.y + a4.z * w2.y + a4.w * w3.y;
            acc.z += a4.x * w0.z + a4.y * w1.z + a4.z * w2.z + a4.w * w3.z;
            acc.w += a4.x * w0.w + a4.y * w1.w + a4.z * w2.w + a4.w * w3.w;
        }
        *(float4*)(Hout + (size_t)(i0 + r) * D + 4 * jg) = acc;
        *(float4*)&Hs[r][4 * jg] = acc;
    }
    __syncthreads();

    const float* Ws[3] = {Wq, Wk, Wv};
    const float* bs[3] = {bq, bk, bv};
    #pragma unroll
    for (int m = 0; m < 3; ++m) {
        float4 acc = *(const float4*)(bs[m] + 4 * jg);
        const float* W = Ws[m];
        #pragma unroll 8
        for (int k4 = 0; k4 < 32; ++k4) {
            const float4 a4 = *(const float4*)&Hs[r][4 * k4];
            const float* wb = W + (size_t)(4 * k4) * D + 4 * jg;
            const float4 w0 = *(const float4*)(wb);
            const float4 w1 = *(const float4*)(wb + D);
            const float4 w2 = *(const float4*)(wb + 2 * D);
            const float4 w3 = *(const float4*)(wb + 3 * D);
            acc.x += a4.x * w0.x + a4.y * w1.x + a4.z * w2.x + a4.w * w3.x;
            acc.y += a4.x * w0.y + a4.y * w1.y + a4.z * w2.y + a4.w * w3.y;
            acc.z += a4.x * w0.z + a4.y * w1.z + a4.z * w2.z + a4.w * w3.z;
            acc.w += a4.x * w0.w + a4.y * w1.w + a4.z * w2.w + a4.w * w3.w;
        }
        if (m == 2) {   // V transposed: Vt[d][row]
            const int i = i0 + r;
            Vt[(size_t)(4 * jg)     * N + i] = (__half)(_Float16)acc.x;
            Vt[(size_t)(4 * jg + 1) * N + i] = (__half)(_Float16)acc.y;
            Vt[(size_t)(4 * jg + 2) * N + i] = (__half)(_Float16)acc.z;
            Vt[(size_t)(4 * jg + 3) * N + i] = (__half)(_Float16)acc.w;
        } else {
            f16x4 hh;
            hh[0] = (_Float16)acc.x; hh[1] = (_Float16)acc.y;
            hh[2] = (_Float16)acc.z; hh[3] = (_Float16)acc.w;
            __half* O = (m == 0) ? Qo : Ko;
            *(f16x4*)(O + (size_t)(i0 + r) * D + 4 * jg) = hh;
        }
    }
}

// ---------------------------------------------------------------------------
// Final: combine partials -> h, then h@Wo+bo -> C (fp32).
// ---------------------------------------------------------------------------
__global__ __launch_bounds__(256) void gemm_bias(const float* __restrict__ accP,
                                                 const float* __restrict__ denP,
                                                 const float* __restrict__ W,
                                                 const float* __restrict__ bias,
                                                 float* __restrict__ C) {
    __shared__ float As[8][D];
    const int tid = threadIdx.x;
    const int r   = tid >> 5;
    const int jg  = tid & 31;
    const int i0  = blockIdx.x * 8;

    {
        const int i = i0 + (tid >> 5);
        const float inv = 1.0f / (denP[i] + denP[N + i]);
        const float4 a0 = ((const float4*)(accP + (size_t)i0 * D))[tid];
        const float4 a1 = ((const float4*)(accP + (size_t)(N + i0) * D))[tid];
        float4 v;
        v.x = (a0.x + a1.x) * inv; v.y = (a0.y + a1.y) * inv;
        v.z = (a0.z + a1.z) * inv; v.w = (a0.w + a1.w) * inv;
        ((float4*)&As[0][0])[tid] = v;
    }
    __syncthreads();

    float4 acc = *(const float4*)(bias + 4 * jg);
    #pragma unroll 8
    for (int k4 = 0; k4 < 32; ++k4) {
        const float4 a4 = *(const float4*)&As[r][4 * k4];
        const float* wb = W + (size_t)(4 * k4) * D + 4 * jg;
        const float4 w0 = *(const float4*)(wb);
        const float4 w1 = *(const float4*)(wb + D);
        const float4 w2 = *(const float4*)(wb + 2 * D);
        const float4 w3 = *(const float4*)(wb + 3 * D);
        acc.x += a4.x * w0.x + a4.y * w1.x + a4.z * w2.x + a4.w * w3.x;
        acc.y += a4.x * w0.y + a4.y * w1.y + a4.z * w2.y + a4.w * w3.y;
        acc.z += a4.x * w0.z + a4.y * w1.z + a4.z * w2.z + a4.w * w3.z;
        acc.w += a4.x * w0.w + a4.y * w1.w + a4.z * w2.w + a4.w * w3.w;
    }
    *(float4*)(C + (size_t)(i0 + r) * D + 4 * jg) = acc;
}

extern "C" void kernel_launch(void* const* d_in, const int* in_sizes, int n_in,
                              void* d_out, int out_size, void* d_ws, size_t ws_size,
                              hipStream_t stream) {
    const float* features = (const float*)d_in[0];
    const int*   mask     = (const int*)d_in[1];
    const float* Wq = (const float*)d_in[2];
    const float* bq = (const float*)d_in[3];
    const float* Wk = (const float*)d_in[4];
    const float* bk = (const float*)d_in[5];
    const float* Wv = (const float*)d_in[6];
    const float* bv = (const float*)d_in[7];
    const float* Wo = (const float*)d_in[8];
    const float* bo = (const float*)d_in[9];
    float* out = (float*)d_out;

    // workspace (~22 MB): bits | Qf | Kf | Vt | accP | denP
    char* base = (char*)d_ws;
    unsigned* bits = (unsigned*)base;                                   // 8 MB
    __half* Qf = (__half*)(base + (size_t)N * 256 * 4);                 // 2 MB
    __half* Kf = Qf + (size_t)N * D;                                    // 2 MB
    __half* Vt = Kf + (size_t)N * D;                                    // 2 MB ([D][N])
    float* accP = (float*)(Vt + (size_t)D * N);                         // 8 MB (2 halves)
    float* denP = accP + (size_t)2 * N * D;                             // 64 KB

    // dispatch 1: mask bits (int4+nibble) + layer-0 QKV (+ out[0] copy)
    bits_qkv<<<N + N / 8, 256, 0, stream>>>(mask, bits,
                                            features, Wq, bq, Wk, bk, Wv, bv,
                                            Qf, Kf, Vt, out);
    // layer 0: dense MFMA flash (split-K x2, unnormalized partials)
    flash_attn<<<256, 256, 0, stream>>>(Qf, Kf, Vt, bits, accP, denP);
    gemmO_qkv<<<N / 8, 256, 0, stream>>>(accP, denP, Wo, bo, out + (size_t)N * D,
                                         Wq + D * D, bq + D, Wk + D * D, bk + D,
                                         Wv + D * D, bv + D, Qf, Kf, Vt);
    // layer 1
    flash_attn<<<256, 256, 0, stream>>>(Qf, Kf, Vt, bits, accP, denP);
    gemm_bias<<<N / 8, 256, 0, stream>>>(accP, denP, Wo + D * D, bo + D,
                                         out + (size_t)2 * N * D);
}

// Round 14
// 660.622 us; speedup vs baseline: 1.4955x; 1.1049x over previous
//
#include <hip/hip_runtime.h>
#include <hip/hip_fp16.h>
#include <math.h>

#define N 8192
#define D 128
#define SPLITK 8   // key splits: grid = 128 q-tiles x 8 = 1024 blocks = 4/CU

typedef _Float16 f16x4 __attribute__((ext_vector_type(4)));
typedef _Float16 f16x8 __attribute__((ext_vector_type(8)));
typedef float    f32x4 __attribute__((ext_vector_type(4)));

// ---------------------------------------------------------------------------
// FUSED: bit-packed mask build (blocks 0..N-1) + layer-0 Q/K/V projection
// (blocks N..N+N/8-1). int4 mask loads (proven pattern, ~43us floor).
// R14: V-transpose write now goes through LDS -> 128 coalesced 16B stores
// per block (was 1024 scalar 2B stores at 64KB stride = divergent scatter).
// ---------------------------------------------------------------------------
__global__ __launch_bounds__(256) void bits_qkv(const int* __restrict__ mask,
                                                unsigned* __restrict__ bits,
                                                const float* __restrict__ A,
                                                const float* __restrict__ Wq, const float* __restrict__ bq,
                                                const float* __restrict__ Wk, const float* __restrict__ bk,
                                                const float* __restrict__ Wv, const float* __restrict__ bv,
                                                __half* __restrict__ Qo, __half* __restrict__ Ko,
                                                __half* __restrict__ Vt,
                                                float* __restrict__ copy_out) {
    __shared__ float As[8][D];
    __shared__ _Float16 Vs[8][D];
    const int tid = threadIdx.x;

    if (blockIdx.x < N) {
        const int i = blockIdx.x;
        __shared__ unsigned char nib[2048];          // 1 nibble-byte per 4 columns
        const int4* row = (const int4*)(mask + (size_t)i * N);
        #pragma unroll
        for (int c = 0; c < 8; ++c) {
            const int idx = tid + c * 256;           // 0..2047, coalesced int4
            const int4 m4 = row[idx];
            nib[idx] = (unsigned char)((m4.x ? 1 : 0) | (m4.y ? 2 : 0) |
                                       (m4.z ? 4 : 0) | (m4.w ? 8 : 0));
        }
        __syncthreads();
        const unsigned long long n8 = *(const unsigned long long*)&nib[8 * tid];
        unsigned word = 0;
        #pragma unroll
        for (int b = 0; b < 8; ++b)
            word |= ((unsigned)((n8 >> (8 * b)) & 0xFull)) << (4 * b);
        bits[(size_t)i * 256 + tid] = word;
        return;
    }

    // ---- layer-0 QKV projection + fused output-0 copy ----
    const int r   = tid >> 5;
    const int jg  = tid & 31;
    const int i0  = (blockIdx.x - N) * 8;

    const float4 av = ((const float4*)(A + (size_t)i0 * D))[tid];
    ((float4*)&As[0][0])[tid] = av;
    ((float4*)(copy_out + (size_t)i0 * D))[tid] = av;
    __syncthreads();

    const float* Ws[3] = {Wq, Wk, Wv};
    const float* bs[3] = {bq, bk, bv};

    #pragma unroll
    for (int m = 0; m < 3; ++m) {
        float4 acc = *(const float4*)(bs[m] + 4 * jg);
        const float* W = Ws[m];
        #pragma unroll 8
        for (int k4 = 0; k4 < 32; ++k4) {
            const float4 a4 = *(const float4*)&As[r][4 * k4];
            const float* wb = W + (size_t)(4 * k4) * D + 4 * jg;
            const float4 w0 = *(const float4*)(wb);
            const float4 w1 = *(const float4*)(wb + D);
            const float4 w2 = *(const float4*)(wb + 2 * D);
            const float4 w3 = *(const float4*)(wb + 3 * D);
            acc.x += a4.x * w0.x + a4.y * w1.x + a4.z * w2.x + a4.w * w3.x;
            acc.y += a4.x * w0.y + a4.y * w1.y + a4.z * w2.y + a4.w * w3.y;
            acc.z += a4.x * w0.z + a4.y * w1.z + a4.z * w2.z + a4.w * w3.z;
            acc.w += a4.x * w0.w + a4.y * w1.w + a4.z * w2.w + a4.w * w3.w;
        }
        if (m == 2) {   // V -> LDS for coalesced transposed write
            Vs[r][4 * jg]     = (_Float16)acc.x;
            Vs[r][4 * jg + 1] = (_Float16)acc.y;
            Vs[r][4 * jg + 2] = (_Float16)acc.z;
            Vs[r][4 * jg + 3] = (_Float16)acc.w;
        } else {
            f16x4 h;
            h[0] = (_Float16)acc.x; h[1] = (_Float16)acc.y;
            h[2] = (_Float16)acc.z; h[3] = (_Float16)acc.w;
            __half* O = (m == 0) ? Qo : Ko;
            *(f16x4*)(O + (size_t)(i0 + r) * D + 4 * jg) = h;
        }
    }
    __syncthreads();
    if (tid < D) {       // one d per thread: 16B coalesced store to Vt[d][i0..i0+7]
        f16x8 v;
        #pragma unroll
        for (int k = 0; k < 8; ++k) v[k] = Vs[k][tid];
        *(f16x8*)(Vt + (size_t)tid * N + i0) = v;
    }
}

// ---------------------------------------------------------------------------
// R14 DENSE MFMA FLASH. Grid 1024 = 128 q-tiles x SPLITK=8 key splits.
// R13 ran grid 256 = 1 block/CU = 1 wave/SIMD: zero TLP, 128 full-drain
// barriers, exposed staging latency -> ~150us. Now 4 blocks/CU (3 resident
// by 41.5KB LDS) overlap staging/barriers; each block does 16 tiles.
// MFMA layout m89-verified (R12/R13 passed absmax 0.0078).
// ---------------------------------------------------------------------------
__global__ __launch_bounds__(256) void flash_attn(const __half* __restrict__ Q,
                                                  const __half* __restrict__ K,
                                                  const __half* __restrict__ Vt,
                                                  const unsigned* __restrict__ bits,
                                                  float* __restrict__ accP,
                                                  float* __restrict__ denP) {
    const int qt   = blockIdx.x >> 3;    // query tile (64 rows)
    const int h    = blockIdx.x & 7;     // key split (1024 keys)
    const int tid  = threadIdx.x;
    const int wave = tid >> 6;
    const int lane = tid & 63;
    const int l15  = lane & 15;
    const int lg   = lane >> 4;          // 0..3

    __shared__ char lds[41472];
    // [0,16384)      K_lds [64 keys][128 d] f16, swz ^((key&7)<<4)
    // [16384,32768)  V_t  [128 d][64 keys] f16, swz ^((d&7)<<4)
    // [32768,40960)  P    [4 waves][16 q][64 keys] f16, swz ^((q&7)<<4)
    // [40960,41472)  mask u32 [64 q][2 words]
    unsigned* mask_lds = (unsigned*)(lds + 40960);

    const int qbase = qt * 64 + wave * 16;

    f16x8 qf[4];
    #pragma unroll
    for (int c = 0; c < 4; ++c)
        qf[c] = *(const f16x8*)(Q + (size_t)(qbase + l15) * D + c * 32 + lg * 8);

    f32x4 Oacc[8];
    #pragma unroll
    for (int ds = 0; ds < 8; ++ds) Oacc[ds] = (f32x4){0.f, 0.f, 0.f, 0.f};
    float den[4] = {0.f, 0.f, 0.f, 0.f};

    const float scale = 0.088388347648318447f;  // 1/sqrt(128)

    for (int t = 0; t < 16; ++t) {
        const int kb = h * 1024 + t * 64;

        // ---- stage K tile + V^T tile, all b128 ----
        #pragma unroll
        for (int cc = 0; cc < 4; ++cc) {
            const int idx  = tid + cc * 256;          // 0..1023
            const int krow = idx >> 4;
            const int dp   = (idx & 15) * 8;
            const f16x8 k8 = *(const f16x8*)(K + (size_t)(kb + krow) * D + dp);
            *(f16x8*)(lds + ((krow * 256 + dp * 2) ^ ((krow & 7) << 4))) = k8;
            const int d    = idx >> 3;
            const int kg   = (idx & 7) * 8;
            const f16x8 v8 = *(const f16x8*)(Vt + (size_t)d * N + kb + kg);
            *(f16x8*)(lds + 16384 + ((d * 128 + kg * 2) ^ ((d & 7) << 4))) = v8;
        }
        if (tid < 128)   // mask: 64 q x 2 words for this key tile
            mask_lds[tid] = bits[(size_t)(qt * 64 + (tid >> 1)) * 256 + (kb >> 5) + (tid & 1)];
        __syncthreads();

        // ---- QK^T + mask + exp + P-write (per wave) ----
        #pragma unroll
        for (int kt = 0; kt < 4; ++kt) {
            f32x4 s = (f32x4){0.f, 0.f, 0.f, 0.f};
            const int key = kt * 16 + l15;
            #pragma unroll
            for (int c = 0; c < 4; ++c) {
                const f16x8 b = *(const f16x8*)(lds +
                    ((key * 256 + (c * 32 + lg * 8) * 2) ^ ((key & 7) << 4)));
                s = __builtin_amdgcn_mfma_f32_16x16x32_f16(qf[c], b, s, 0, 0, 0);
            }
            #pragma unroll
            for (int r = 0; r < 4; ++r) {
                const int q  = lg * 4 + r;
                const unsigned mw = mask_lds[(wave * 16 + q) * 2 + (key >> 5)];
                const float p = ((mw >> (key & 31)) & 1u) ? __expf(s[r] * scale) : 0.f;
                den[r] += p;
                *(_Float16*)(lds + 32768 + wave * 2048 +
                             ((q * 128 + key * 2) ^ ((q & 7) << 4))) = (_Float16)p;
            }
        }

        // ---- PV: O += P @ V ----
        #pragma unroll
        for (int kc = 0; kc < 2; ++kc) {
            const f16x8 a = *(const f16x8*)(lds + 32768 + wave * 2048 +
                ((l15 * 128 + (kc * 32 + lg * 8) * 2) ^ ((l15 & 7) << 4)));
            #pragma unroll
            for (int ds = 0; ds < 8; ++ds) {
                const int d = ds * 16 + l15;
                const f16x8 b = *(const f16x8*)(lds + 16384 +
                    ((d * 128 + (kc * 32 + lg * 8) * 2) ^ ((d & 7) << 4)));
                Oacc[ds] = __builtin_amdgcn_mfma_f32_16x16x32_f16(a, b, Oacc[ds], 0, 0, 0);
            }
        }
        __syncthreads();
    }

    // denominator: reduce across the 16 key-lanes of each row-group
    #pragma unroll
    for (int r = 0; r < 4; ++r) {
        den[r] += __shfl_xor(den[r], 1);
        den[r] += __shfl_xor(den[r], 2);
        den[r] += __shfl_xor(den[r], 4);
        den[r] += __shfl_xor(den[r], 8);
    }

    // store UNNORMALIZED partials (combine folded into the next GEMM's stage)
    float* ap = accP + (size_t)h * N * D;
    #pragma unroll
    for (int ds = 0; ds < 8; ++ds)
        #pragma unroll
        for (int r = 0; r < 4; ++r)
            ap[(size_t)(qbase + lg * 4 + r) * D + ds * 16 + l15] = Oacc[ds][r];
    if (l15 == 0) {
        #pragma unroll
        for (int r = 0; r < 4; ++r)
            denP[h * N + qbase + lg * 4 + r] = den[r];
    }
}

// ---------------------------------------------------------------------------
// Combine SPLITK partials -> h, then h@Wo+bo -> Hout, then next Q/K/Vt.
// ---------------------------------------------------------------------------
__global__ __launch_bounds__(256) void gemmO_qkv(const float* __restrict__ accP,
                                                 const float* __restrict__ denP,
                                                 const float* __restrict__ Wo, const float* __restrict__ bo,
                                                 float* __restrict__ Hout,
                                                 const float* __restrict__ Wq, const float* __restrict__ bq,
                                                 const float* __restrict__ Wk, const float* __restrict__ bk,
                                                 const float* __restrict__ Wv, const float* __restrict__ bv,
                                                 __half* __restrict__ Qo, __half* __restrict__ Ko,
                                                 __half* __restrict__ Vt) {
    __shared__ float As[8][D];
    __shared__ float Hs[8][D];
    __shared__ _Float16 Vs[8][D];
    const int tid = threadIdx.x;
    const int r   = tid >> 5;
    const int jg  = tid & 31;
    const int i0  = blockIdx.x * 8;

    {
        const int i = i0 + (tid >> 5);
        float dsum = 0.f;
        float4 v = {0.f, 0.f, 0.f, 0.f};
        #pragma unroll
        for (int s = 0; s < SPLITK; ++s) {
            dsum += denP[s * N + i];
            const float4 a = ((const float4*)(accP + (size_t)s * N * D + (size_t)i0 * D))[tid];
            v.x += a.x; v.y += a.y; v.z += a.z; v.w += a.w;
        }
        const float inv = 1.0f / dsum;
        v.x *= inv; v.y *= inv; v.z *= inv; v.w *= inv;
        ((float4*)&As[0][0])[tid] = v;
    }
    __syncthreads();

    {
        float4 acc = *(const float4*)(bo + 4 * jg);
        #pragma unroll 8
        for (int k4 = 0; k4 < 32; ++k4) {
            const float4 a4 = *(const float4*)&As[r][4 * k4];
            const float* wb = Wo + (size_t)(4 * k4) * D + 4 * jg;
            const float4 w0 = *(const float4*)(wb);
            const float4 w1 = *(const float4*)(wb + D);
            const float4 w2 = *(const float4*)(wb + 2 * D);
            const float4 w3 = *(const float4*)(wb + 3 * D);
            acc.x += a4.x * w0.x + a4.y * w1.x + a4.z * w2.x + a4.w * w3.x;
            acc.y += a4.x * w0.y + a4.y * w1.y + a4.z * w2.y + a4.w * w3.y;
            acc.z += a4.x * w0.z + a4.y * w1.z + a4.z * w2.z + a4.w * w3.z;
            acc.w += a4.x * w0.w + a4.y * w1.w + a4.z * w2.w + a4.w * w3.w;
        }
        *(float4*)(Hout + (size_t)(i0 + r) * D + 4 * jg) = acc;
        *(float4*)&Hs[r][4 * jg] = acc;
    }
    __syncthreads();

    const float* Ws[3] = {Wq, Wk, Wv};
    const float* bs[3] = {bq, bk, bv};
    #pragma unroll
    for (int m = 0; m < 3; ++m) {
        float4 acc = *(const float4*)(bs[m] + 4 * jg);
        const float* W = Ws[m];
        #pragma unroll 8
        for (int k4 = 0; k4 < 32; ++k4) {
            const float4 a4 = *(const float4*)&Hs[r][4 * k4];
            const float* wb = W + (size_t)(4 * k4) * D + 4 * jg;
            const float4 w0 = *(const float4*)(wb);
            const float4 w1 = *(const float4*)(wb + D);
            const float4 w2 = *(const float4*)(wb + 2 * D);
            const float4 w3 = *(const float4*)(wb + 3 * D);
            acc.x += a4.x * w0.x + a4.y * w1.x + a4.z * w2.x + a4.w * w3.x;
            acc.y += a4.x * w0.y + a4.y * w1.y + a4.z * w2.y + a4.w * w3.y;
            acc.z += a4.x * w0.z + a4.y * w1.z + a4.z * w2.z + a4.w * w3.z;
            acc.w += a4.x * w0.w + a4.y * w1.w + a4.z * w2.w + a4.w * w3.w;
        }
        if (m == 2) {
            Vs[r][4 * jg]     = (_Float16)acc.x;
            Vs[r][4 * jg + 1] = (_Float16)acc.y;
            Vs[r][4 * jg + 2] = (_Float16)acc.z;
            Vs[r][4 * jg + 3] = (_Float16)acc.w;
        } else {
            f16x4 hh;
            hh[0] = (_Float16)acc.x; hh[1] = (_Float16)acc.y;
            hh[2] = (_Float16)acc.z; hh[3] = (_Float16)acc.w;
            __half* O = (m == 0) ? Qo : Ko;
            *(f16x4*)(O + (size_t)(i0 + r) * D + 4 * jg) = hh;
        }
    }
    __syncthreads();
    if (tid < D) {
        f16x8 v;
        #pragma unroll
        for (int k = 0; k < 8; ++k) v[k] = Vs[k][tid];
        *(f16x8*)(Vt + (size_t)tid * N + i0) = v;
    }
}

// ---------------------------------------------------------------------------
// Final: combine partials -> h, then h@Wo+bo -> C (fp32).
// ---------------------------------------------------------------------------
__global__ __launch_bounds__(256) void gemm_bias(const float* __restrict__ accP,
                                                 const float* __restrict__ denP,
                                                 const float* __restrict__ W,
                                                 const float* __restrict__ bias,
                                                 float* __restrict__ C) {
    __shared__ float As[8][D];
    const int tid = threadIdx.x;
    const int r   = tid >> 5;
    const int jg  = tid & 31;
    const int i0  = blockIdx.x * 8;

    {
        const int i = i0 + (tid >> 5);
        float dsum = 0.f;
        float4 v = {0.f, 0.f, 0.f, 0.f};
        #pragma unroll
        for (int s = 0; s < SPLITK; ++s) {
            dsum += denP[s * N + i];
            const float4 a = ((const float4*)(accP + (size_t)s * N * D + (size_t)i0 * D))[tid];
            v.x += a.x; v.y += a.y; v.z += a.z; v.w += a.w;
        }
        const float inv = 1.0f / dsum;
        v.x *= inv; v.y *= inv; v.z *= inv; v.w *= inv;
        ((float4*)&As[0][0])[tid] = v;
    }
    __syncthreads();

    float4 acc = *(const float4*)(bias + 4 * jg);
    #pragma unroll 8
    for (int k4 = 0; k4 < 32; ++k4) {
        const float4 a4 = *(const float4*)&As[r][4 * k4];
        const float* wb = W + (size_t)(4 * k4) * D + 4 * jg;
        const float4 w0 = *(const float4*)(wb);
        const float4 w1 = *(const float4*)(wb + D);
        const float4 w2 = *(const float4*)(wb + 2 * D);
        const float4 w3 = *(const float4*)(wb + 3 * D);
        acc.x += a4.x * w0.x + a4.y * w1.x + a4.z * w2.x + a4.w * w3.x;
        acc.y += a4.x * w0.y + a4.y * w1.y + a4.z * w2.y + a4.w * w3.y;
        acc.z += a4.x * w0.z + a4.y * w1.z + a4.z * w2.z + a4.w * w3.z;
        acc.w += a4.x * w0.w + a4.y * w1.w + a4.z * w2.w + a4.w * w3.w;
    }
    *(float4*)(C + (size_t)(i0 + r) * D + 4 * jg) = acc;
}

extern "C" void kernel_launch(void* const* d_in, const int* in_sizes, int n_in,
                              void* d_out, int out_size, void* d_ws, size_t ws_size,
                              hipStream_t stream) {
    const float* features = (const float*)d_in[0];
    const int*   mask     = (const int*)d_in[1];
    const float* Wq = (const float*)d_in[2];
    const float* bq = (const float*)d_in[3];
    const float* Wk = (const float*)d_in[4];
    const float* bk = (const float*)d_in[5];
    const float* Wv = (const float*)d_in[6];
    const float* bv = (const float*)d_in[7];
    const float* Wo = (const float*)d_in[8];
    const float* bo = (const float*)d_in[9];
    float* out = (float*)d_out;

    // workspace (~46.5 MB): bits | Qf | Kf | Vt | accP(8) | denP(8)
    char* base = (char*)d_ws;
    unsigned* bits = (unsigned*)base;                                   // 8 MB
    __half* Qf = (__half*)(base + (size_t)N * 256 * 4);                 // 2 MB
    __half* Kf = Qf + (size_t)N * D;                                    // 2 MB
    __half* Vt = Kf + (size_t)N * D;                                    // 2 MB ([D][N])
    float* accP = (float*)(Vt + (size_t)D * N);                         // 32 MB (8 splits)
    float* denP = accP + (size_t)SPLITK * N * D;                        // 256 KB

    // dispatch 1: mask bits (int4+nibble) + layer-0 QKV (+ out[0] copy)
    bits_qkv<<<N + N / 8, 256, 0, stream>>>(mask, bits,
                                            features, Wq, bq, Wk, bk, Wv, bv,
                                            Qf, Kf, Vt, out);
    // layer 0: dense MFMA flash (split-K x8 -> 4 blocks/CU)
    flash_attn<<<128 * SPLITK, 256, 0, stream>>>(Qf, Kf, Vt, bits, accP, denP);
    gemmO_qkv<<<N / 8, 256, 0, stream>>>(accP, denP, Wo, bo, out + (size_t)N * D,
                                         Wq + D * D, bq + D, Wk + D * D, bk + D,
                                         Wv + D * D, bv + D, Qf, Kf, Vt);
    // layer 1
    flash_attn<<<128 * SPLITK, 256, 0, stream>>>(Qf, Kf, Vt, bits, accP, denP);
    gemm_bias<<<N / 8, 256, 0, stream>>>(accP, denP, Wo + D * D, bo + D,
                                         out + (size_t)2 * N * D);
}